// Round 9
// baseline (8256.190 us; speedup 1.0000x reference)
//
#include <hip/hip_runtime.h>
#include <math.h>

// Problem constants
#define EMBD 400
#define HIDD 300
#define KEYD 128
#define VALD 128
#define NVOC 33
#define TT 256
#define BB 256
#define SS 512
#define WIH_LD 528          // EMB+VAL
#define GDIM 1200           // 4*HID
#define KTOT 428            // ctx(128)+h(300)
#define KPAD 432            // padded
#define NK2 216             // KPAD/2 (k-pairs)
#define NI2 152             // padded phi i-pairs (150 real + 2 zero)
#define NBLK 256            // one block per batch row

typedef unsigned int u32;
typedef unsigned int u32x4 __attribute__((ext_vector_type(4)));
typedef _Float16 f16x2 __attribute__((ext_vector_type(2)));

__device__ __forceinline__ f16x2 h2u(u32 u) {
    return __builtin_bit_cast(f16x2, u);
}
__device__ __forceinline__ float fdot2_(u32 w, f16x2 x, float c) {
    return __builtin_amdgcn_fdot2(h2u(w), x, c, false);
}
__device__ __forceinline__ u32 packh2(float a, float b) {
    f16x2 p; p[0] = (_Float16)a; p[1] = (_Float16)b;
    return __builtin_bit_cast(u32, p);
}
__device__ __forceinline__ float sigmoidf_(float x) {
    return 1.f / (1.f + __expf(-x));
}
__device__ __forceinline__ float tanh_f(float x) {
    float ax = fabsf(x);
    if (ax > 15.f) return x > 0.f ? 1.f : -1.f;
    float e = __expf(2.f * x);
    return (e - 1.f) / (e + 1.f);
}

// ---------------- Precompute: E2[v][j] = b_ih[j]+b_hh[j]+emb[v]·W_ih[j][:400]
__global__ __launch_bounds__(256) void p_e2(
    const float* __restrict__ emb, const float* __restrict__ Wih,
    const float* __restrict__ bih, const float* __restrict__ bhh,
    float* __restrict__ E2)
{
    __shared__ float es[EMBD];
    const int v = blockIdx.x;
    for (int i = threadIdx.x; i < EMBD; i += 256) es[i] = emb[v * EMBD + i];
    __syncthreads();
    for (int j = threadIdx.x; j < GDIM; j += 256) {
        const float* wr = &Wih[(size_t)j * WIH_LD];
        float s0 = 0.f, s1 = 0.f, s2 = 0.f, s3 = 0.f;
        for (int e = 0; e < EMBD; e += 4) {
            s0 += es[e]     * wr[e];
            s1 += es[e + 1] * wr[e + 1];
            s2 += es[e + 2] * wr[e + 2];
            s3 += es[e + 3] * wr[e + 3];
        }
        E2[v * GDIM + j] = bih[j] + bhh[j] + ((s0 + s1) + (s2 + s3));
    }
}

// ---------------- Precompute: W2[k2][j] = pack_f16(W[2k2][j], W[2k2+1][j]);
// phi2[i2][k] = pack_f16(phi_w[k][2i2], phi_w[k][2i2+1])
__global__ __launch_bounds__(256) void p_w2(
    const float* __restrict__ Wih, const float* __restrict__ Whh,
    const float* __restrict__ phi_w,
    u32* __restrict__ W2, u32* __restrict__ phi2)
{
    const int stride = gridDim.x * 256;
    const int tot1 = NK2 * GDIM;
    for (int m = blockIdx.x * 256 + threadIdx.x; m < tot1; m += stride) {
        int k2 = m / GDIM, j = m - k2 * GDIM;
        float w0 = 0.f, w1 = 0.f;
        int k0 = 2 * k2, k1 = 2 * k2 + 1;
        if (k0 < KEYD)      w0 = Wih[(size_t)j * WIH_LD + EMBD + k0];
        else if (k0 < KTOT) w0 = Whh[(size_t)j * HIDD + (k0 - KEYD)];
        if (k1 < KEYD)      w1 = Wih[(size_t)j * WIH_LD + EMBD + k1];
        else if (k1 < KTOT) w1 = Whh[(size_t)j * HIDD + (k1 - KEYD)];
        W2[m] = packh2(w0, w1);
    }
    const int tot2 = NI2 * KEYD;
    for (int m = blockIdx.x * 256 + threadIdx.x; m < tot2; m += stride) {
        int i2 = m >> 7, k = m & 127;
        float w0 = 0.f, w1 = 0.f;
        if (2 * i2 < HIDD)     w0 = phi_w[(size_t)k * HIDD + 2 * i2];
        if (2 * i2 + 1 < HIDD) w1 = phi_w[(size_t)k * HIDD + 2 * i2 + 1];
        phi2[m] = packh2(w0, w1);
    }
}

// ---------------- Precompute: K -> f16 [b][s][d]; V -> f16 pairs [b][s2][d][2]
__global__ __launch_bounds__(1024) void p_kv(
    const float* __restrict__ keys, const float* __restrict__ values,
    _Float16* __restrict__ kh, _Float16* __restrict__ vh2)
{
    size_t i = (size_t)blockIdx.x * 1024 + threadIdx.x;  // S*B*128 exactly
    int s = (int)(i >> 15);
    int r = (int)(i & 32767);
    int b = r >> 7, d = r & 127;
    kh[(((size_t)b * SS + s) << 7) + d] = (_Float16)keys[i];
    size_t vd = ((((size_t)b * 256 + (s >> 1)) << 7) + d) * 2 + (s & 1);
    vh2[vd] = (_Float16)values[i];
}

// ---------------- logits: threads 512..1023; 16 lanes per vocab, f32
__device__ __forceinline__ void logits33(
    int tid, int b, int t, const float* __restrict__ projw,
    const float* __restrict__ projb, float* __restrict__ out,
    const float* __restrict__ h_s, const float* __restrict__ ctx_s)
{
    if (tid >= 512) {
        const int idx = tid - 512;
        const int l = idx & 15;
        const int vs = idx >> 4;                  // 0..31
        #pragma unroll
        for (int rep = 0; rep < 2; ++rep) {
            const int v = vs + rep * 32;
            if (v < NVOC) {
                const float* pw = projw + (size_t)v * KTOT;
                float s = 0.f;
                for (int k = l; k < KTOT; k += 16) {
                    float u = (k < HIDD) ? h_s[k] : ctx_s[k - HIDD];
                    s += pw[k] * u;
                }
                #pragma unroll
                for (int off = 8; off; off >>= 1) s += __shfl_xor(s, off);
                if (l == 0)
                    out[((size_t)t * BB + b) * NVOC + v] = s + projb[v];
            }
        }
    }
}

// ---------------- attend for one row (1024 threads), f16 dot2 paths.
// OVL: overlap logits(t) on upper 512 during q-partial phase.
// 5 barriers: qpart | energy(+fold q, +V prefetch) | softmax(1 wave) | PV | red
template<int OVL>
__device__ __forceinline__ void attend1(
    const int tid, const int b, const int t,
    const _Float16* __restrict__ kh, const _Float16* __restrict__ vh2,
    const u32* __restrict__ phi2, const float* __restrict__ pb_s,
    const float* __restrict__ projw, const float* __restrict__ projb,
    float* __restrict__ out,
    float* h_s, float* ctx_s, float* att, u32* att2,
    float (*qp)[KEYD], float (*cpart)[VALD],
    _Float16* xinh, const u32* xin2)
{
    // ---- q partial: q[k] = sum_i h[i]*phi[i][k]; lower 512 (4 i2-slices of 38)
    if (tid < 512) {
        const int k = tid & 127, sl = tid >> 7;
        const int i20 = sl * 38;
        float acc = 0.f;
        #pragma unroll 19
        for (int i2 = i20; i2 < i20 + 38; ++i2)
            acc = fdot2_(phi2[i2 * 128 + k], h2u(xin2[64 + i2]), acc);
        qp[sl][k] = acc;
    } else if (OVL) {
        logits33(tid, b, t, projw, projb, out, h_s, ctx_s);
    }
    __syncthreads();

    // ---- energy: all 1024; fold q slice on the fly; 64 s-groups x 16 lanes
    u32x4 vpre[8];
    {
        const int l16 = tid & 15, sg = tid >> 4;    // sg 0..63
        const int ia = l16 * 2, ib = ia + 1;
        const float4* pb4 = reinterpret_cast<const float4*>(pb_s);
        const float4* q0 = reinterpret_cast<const float4*>(qp[0]);
        const float4* q1 = reinterpret_cast<const float4*>(qp[1]);
        const float4* q2 = reinterpret_cast<const float4*>(qp[2]);
        const float4* q3 = reinterpret_cast<const float4*>(qp[3]);
        float4 qa, qb;
        qa.x = pb4[ia].x + q0[ia].x + q1[ia].x + q2[ia].x + q3[ia].x;
        qa.y = pb4[ia].y + q0[ia].y + q1[ia].y + q2[ia].y + q3[ia].y;
        qa.z = pb4[ia].z + q0[ia].z + q1[ia].z + q2[ia].z + q3[ia].z;
        qa.w = pb4[ia].w + q0[ia].w + q1[ia].w + q2[ia].w + q3[ia].w;
        qb.x = pb4[ib].x + q0[ib].x + q1[ib].x + q2[ib].x + q3[ib].x;
        qb.y = pb4[ib].y + q0[ib].y + q1[ib].y + q2[ib].y + q3[ib].y;
        qb.z = pb4[ib].z + q0[ib].z + q1[ib].z + q2[ib].z + q3[ib].z;
        qb.w = pb4[ib].w + q0[ib].w + q1[ib].w + q2[ib].w + q3[ib].w;
        f16x2 q2a, q2b, q2c, q2d;
        q2a[0] = (_Float16)qa.x; q2a[1] = (_Float16)qa.y;
        q2b[0] = (_Float16)qa.z; q2b[1] = (_Float16)qa.w;
        q2c[0] = (_Float16)qb.x; q2c[1] = (_Float16)qb.y;
        q2d[0] = (_Float16)qb.z; q2d[1] = (_Float16)qb.w;
        const _Float16* krow = kh + (((size_t)b * SS) << 7);
        #pragma unroll
        for (int p = 0; p < 8; ++p) {
            int s = p * 64 + sg;
            const u32x4* kp = reinterpret_cast<const u32x4*>(krow + ((size_t)s << 7));
            u32x4 w = kp[l16];
            float e = fdot2_(w.x, q2a, 0.f);
            e = fdot2_(w.y, q2b, e);
            e = fdot2_(w.z, q2c, e);
            e = fdot2_(w.w, q2d, e);
            e += __shfl_xor(e, 1);
            e += __shfl_xor(e, 2);
            e += __shfl_xor(e, 4);
            e += __shfl_xor(e, 8);
            if (l16 == 0) att[s] = e;
        }
    }
    // ---- V prefetch into registers (consumed in PV after softmax)
    {
        const int v4 = tid & 31, sg5 = tid >> 5;   // sg5 0..31
        const u32* vrow = reinterpret_cast<const u32*>(vh2) + (((size_t)b * 256) << 7);
        #pragma unroll
        for (int i = 0; i < 8; ++i) {
            const u32x4* vp = reinterpret_cast<const u32x4*>(
                vrow + ((size_t)(sg5 * 8 + i) << 7));
            vpre[i] = vp[v4];
        }
    }
    __syncthreads();

    // ---- softmax over 512 energies by wave 0 (8 per lane); writes f16 pairs
    if (tid < 64) {
        const float4* a4 = reinterpret_cast<const float4*>(att);
        float4 e0 = a4[tid * 2], e1 = a4[tid * 2 + 1];
        float m = fmaxf(fmaxf(fmaxf(e0.x, e0.y), fmaxf(e0.z, e0.w)),
                        fmaxf(fmaxf(e1.x, e1.y), fmaxf(e1.z, e1.w)));
        #pragma unroll
        for (int off = 32; off; off >>= 1) m = fmaxf(m, __shfl_xor(m, off));
        float p0 = __expf(e0.x - m), p1 = __expf(e0.y - m);
        float p2 = __expf(e0.z - m), p3 = __expf(e0.w - m);
        float p4 = __expf(e1.x - m), p5 = __expf(e1.y - m);
        float p6 = __expf(e1.z - m), p7 = __expf(e1.w - m);
        float ss = ((p0 + p1) + (p2 + p3)) + ((p4 + p5) + (p6 + p7));
        #pragma unroll
        for (int off = 32; off; off >>= 1) ss += __shfl_xor(ss, off);
        float inv = 1.f / ss;
        att2[tid * 4 + 0] = packh2(p0 * inv, p1 * inv);
        att2[tid * 4 + 1] = packh2(p2 * inv, p3 * inv);
        att2[tid * 4 + 2] = packh2(p4 * inv, p5 * inv);
        att2[tid * 4 + 3] = packh2(p6 * inv, p7 * inv);
    }
    __syncthreads();

    // ---- PV: pure dot2 from prefetched V; 32 s2-groups x 32 lanes
    {
        const int v4 = tid & 31, sg5 = tid >> 5;
        float4 a = make_float4(0.f, 0.f, 0.f, 0.f);
        #pragma unroll
        for (int i = 0; i < 8; ++i) {
            f16x2 wt2 = h2u(att2[sg5 * 8 + i]);
            a.x = fdot2_(vpre[i].x, wt2, a.x);
            a.y = fdot2_(vpre[i].y, wt2, a.y);
            a.z = fdot2_(vpre[i].z, wt2, a.z);
            a.w = fdot2_(vpre[i].w, wt2, a.w);
        }
        *reinterpret_cast<float4*>(&cpart[sg5][v4 * 4]) = a;
    }
    __syncthreads();
    if (tid < VALD) {
        float s = 0.f;
        #pragma unroll
        for (int g = 0; g < 32; ++g) s += cpart[g][tid];
        ctx_s[tid] = s;
        xinh[tid] = (_Float16)s;       // staged for next gates GEMM
    }
    __syncthreads();
}

// ---------------- main body: one persistent block per batch row ------------
__global__ void __launch_bounds__(1024, 4) decoder_dot(
    const int* __restrict__ input,
    const _Float16* __restrict__ kh, const _Float16* __restrict__ vh2,
    const u32* __restrict__ phi2, const float* __restrict__ phi_b,
    const float* __restrict__ h0, const float* __restrict__ c0,
    const float* __restrict__ projw, const float* __restrict__ projb,
    const float* __restrict__ E2, const u32* __restrict__ W2,
    float* __restrict__ out)
{
    const int tid = threadIdx.x;
    const int b = blockIdx.x;

    __shared__ float h_s[HIDD];
    __shared__ float c_s[HIDD];
    __shared__ float ctx_s[VALD];
    __shared__ __align__(16) _Float16 xinh[448];     // [ctx 0..127|h 128..427|0]
    __shared__ __align__(16) float gp[3 * GDIM];     // 3 k-slice partials
    __shared__ __align__(16) float att[SS];
    __shared__ __align__(16) u32 att2[SS / 2];       // packed f16 att pairs
    __shared__ __align__(16) float qp[4][KEYD];
    __shared__ __align__(16) float cpart[32][VALD];  // 16 KB
    __shared__ __align__(16) float pb_s[KEYD];
    __shared__ int xcol[TT];

    const u32* xin2 = reinterpret_cast<const u32*>(xinh);

    // ---- init h, c, xinh-h part, pad; preload phi_b + input column
    for (int j = tid; j < HIDD; j += 1024) {
        float hv = h0[j];
        h_s[j] = hv;
        c_s[j] = c0[j];
        xinh[VALD + j] = (_Float16)hv;
    }
    if (tid < 448 - KTOT) xinh[KTOT + tid] = (_Float16)0.f;
    if (tid < KEYD) pb_s[tid] = phi_b[tid];
    if (tid >= 512 && tid < 512 + TT) xcol[tid - 512] = input[(tid - 512) * BB + b];
    __syncthreads();

    // ctx(-1) = attend(h_init); no logits overlap
    attend1<0>(tid, b, 0, kh, vh2, phi2, pb_s, projw, projb, out,
               h_s, ctx_s, att, att2, qp, cpart, xinh, xin2);

    #pragma unroll 1
    for (int t = 0; t < TT; ++t) {
        // ---- gates GEMM: gl[j] = sum_k xin[k]*W[k][j] via f16 dot2.
        // 900 workers: 300 j-quads x 3 k2-slices of 72.
        if (tid < 900) {
            const int c = tid / 300;
            const int q = tid - c * 300;
            const u32* Wp = W2 + (size_t)(c * 72) * GDIM + 4 * q;
            const u32* xp = xin2 + c * 72;
            float a0 = 0.f, a1 = 0.f, a2 = 0.f, a3 = 0.f;
            #pragma unroll 8
            for (int k2 = 0; k2 < 72; ++k2) {
                f16x2 x2 = h2u(xp[k2]);
                u32x4 w = *reinterpret_cast<const u32x4*>(Wp + (size_t)k2 * GDIM);
                a0 = fdot2_(w.x, x2, a0);
                a1 = fdot2_(w.y, x2, a1);
                a2 = fdot2_(w.z, x2, a2);
                a3 = fdot2_(w.w, x2, a3);
            }
            reinterpret_cast<float4*>(gp + c * GDIM)[q] =
                make_float4(a0, a1, a2, a3);
        }
        __syncthreads();

        // ---- cell update (+E2 embedding gather); 300 threads, one j each
        if (tid < HIDD) {
            const int j = tid;
            const float* e2r = E2 + (size_t)xcol[t] * GDIM;
            float gi = gp[j]
                     + gp[GDIM + j]
                     + gp[2 * GDIM + j]            + e2r[j];
            float gf = gp[HIDD + j]
                     + gp[GDIM + HIDD + j]
                     + gp[2 * GDIM + HIDD + j]     + e2r[HIDD + j];
            float gg = gp[2 * HIDD + j]
                     + gp[GDIM + 2 * HIDD + j]
                     + gp[2 * GDIM + 2 * HIDD + j] + e2r[2 * HIDD + j];
            float go = gp[3 * HIDD + j]
                     + gp[GDIM + 3 * HIDD + j]
                     + gp[2 * GDIM + 3 * HIDD + j] + e2r[3 * HIDD + j];
            float ig = sigmoidf_(gi);
            float fg = sigmoidf_(gf);
            float gt = tanh_f(gg);
            float og = sigmoidf_(go);
            float cn = fg * c_s[j] + ig * gt;
            c_s[j] = cn;
            float hv = og * tanh_f(cn);
            h_s[j] = hv;
            xinh[VALD + j] = (_Float16)hv;
        }
        __syncthreads();

        // ---- attend(h(t)) -> ctx(t), logits(t) overlapped on upper 512.
        if (t < TT - 1) {
            attend1<1>(tid, b, t, kh, vh2, phi2, pb_s, projw, projb, out,
                       h_s, ctx_s, att, att2, qp, cpart, xinh, xin2);
        } else {
            logits33(tid, b, t, projw, projb, out, h_s, ctx_s);
        }
    }
}

// =====================================================================
extern "C" void kernel_launch(void* const* d_in, const int* in_sizes, int n_in,
                              void* d_out, int out_size, void* d_ws, size_t ws_size,
                              hipStream_t stream)
{
    const int*   input     = (const int*)  d_in[0];
    const float* keys      = (const float*)d_in[1];
    const float* values    = (const float*)d_in[2];
    const float* embedding = (const float*)d_in[3];
    const float* phi_w     = (const float*)d_in[4];
    const float* phi_b     = (const float*)d_in[5];
    const float* h0        = (const float*)d_in[6];
    const float* c0        = (const float*)d_in[7];
    const float* W_ih      = (const float*)d_in[8];
    const float* b_ih      = (const float*)d_in[9];
    const float* W_hh      = (const float*)d_in[10];
    const float* b_hh      = (const float*)d_in[11];
    const float* proj_w    = (const float*)d_in[12];
    const float* proj_b    = (const float*)d_in[13];
    float* out = (float*)d_out;

    char* base = (char*)d_ws;
    size_t off = 0;
    auto alloc = [&](size_t bytes) {
        size_t o = off;
        off = (off + bytes + 255) & ~(size_t)255;
        return o;
    };
    size_t oE2   = alloc((size_t)NVOC * GDIM * 4);       // 158 KB
    size_t oPhi  = alloc((size_t)NI2 * KEYD * 4);        // 78 KB
    size_t oW2   = alloc((size_t)NK2 * GDIM * 4);        // 1.04 MB
    size_t oKh   = alloc((size_t)BB * SS * KEYD * 2);    // 33.6 MB
    size_t oVh   = alloc((size_t)BB * SS * VALD * 2);    // 33.6 MB
    (void)off;

    float* E2    = (float*)(base + oE2);
    u32* phi2    = (u32*)(base + oPhi);
    u32* W2      = (u32*)(base + oW2);
    _Float16* kh = (_Float16*)(base + oKh);
    _Float16* vh2= (_Float16*)(base + oVh);

    p_e2<<<NVOC, 256, 0, stream>>>(embedding, W_ih, b_ih, b_hh, E2);
    p_w2<<<2048, 256, 0, stream>>>(W_ih, W_hh, phi_w, W2, phi2);
    p_kv<<<(SS * BB * KEYD) / 1024, 1024, 0, stream>>>(keys, values, kh, vh2);

    decoder_dot<<<NBLK, 1024, 0, stream>>>(
        input, kh, vh2, phi2, phi_b, h0, c0,
        proj_w, proj_b, E2, W2, out);
}